// Round 5
// baseline (251.540 us; speedup 1.0000x reference)
//
#include <hip/hip_runtime.h>
#include <math.h>

typedef __attribute__((ext_vector_type(8)))  __bf16   bf16x8;
typedef __attribute__((ext_vector_type(4)))  float    f32x4;
typedef __attribute__((ext_vector_type(16))) float    f32x16;
typedef __attribute__((ext_vector_type(4)))  unsigned u32x4;
typedef __attribute__((ext_vector_type(2)))  unsigned u32x2;

__device__ __forceinline__ unsigned short f2bf(float f) {
    unsigned u = __builtin_bit_cast(unsigned, f);
    u += 0x7fffu + ((u >> 16) & 1u);
    return (unsigned short)(u >> 16);
}
__device__ __forceinline__ float bf2f(unsigned short b) {
    unsigned u = ((unsigned)b) << 16;
    return __builtin_bit_cast(float, u);
}
__device__ __forceinline__ unsigned swz3(int key) { return (unsigned)((key ^ (key >> 3)) & 7); }
__device__ __forceinline__ bf16x8 ldfrag(const char* p) { return __builtin_bit_cast(bf16x8, *(const u32x4*)p); }

// ---------------------------------------------------------------------------
// prep: pack W into MFMA B-fragment layout (bf16).
// For each layer: frag element (kk, nt, lane, e) = W[f][h] with
//   f = kk*16 + (lane>>5)*8 + e + (nt>=2 ? F : 0)   (nt>=2 -> Wbot)
//   h = (nt&1)*32 + (lane&31)
// Flat: wpk[base + ((kk*4+nt)*64 + lane)*8 + e].
// Bases (elems): L0 @0 (2048), L1 @2048, L2 @18432, L3 @34816 (16384 each).
__global__ __launch_bounds__(256)
void prep(const float* __restrict__ W0, const float* __restrict__ W1,
          const float* __restrict__ W2, const float* __restrict__ W3,
          unsigned short* __restrict__ wpk)
{
    int id = blockIdx.x * 256 + threadIdx.x;
    if (id >= 51200) return;
    float v;
    if (id < 2048) {
        int j = id;
        int e = j & 7, lane = (j >> 3) & 63, nt = (j >> 9) & 3;
        int f = ((lane >> 5) << 3) + e + ((nt >= 2) ? 16 : 0);
        int h = ((nt & 1) << 5) + (lane & 31);
        v = W0[f * 64 + h];
    } else {
        int jid = id - 2048;
        int l = jid >> 14;            // 0,1,2 -> layers 1,2,3
        int j = jid & 16383;
        int e = j & 7, lane = (j >> 3) & 63, nt = (j >> 9) & 3, kk = j >> 11;
        int f = kk * 16 + ((lane >> 5) << 3) + e + ((nt >= 2) ? 128 : 0);
        int h = ((nt & 1) << 5) + (lane & 31);
        const float* W = (l == 0) ? W1 : (l == 1) ? W2 : W3;
        int H = (l == 2) ? 4 : 64;
        v = (h < H) ? W[f * H + h] : 0.f;
    }
    wpk[id] = f2bf(v);
}

// ---------------------------------------------------------------------------
// tgen: P[b][i][j] = round_bf16( round_bf16(exp(exp(-d*p))) / rowsum ), plus
// per-block column-sum partials pcol[b*64+blk][j] (f32, sums of rounded P).
__global__ __launch_bounds__(256, 4)
void tgen(const float* __restrict__ coords, const float* __restrict__ psq,
          unsigned short* __restrict__ Tg, float* __restrict__ pcol)
{
    __shared__ float4 sc[1024];
    __shared__ float scol[4][1024];
    const int t = threadIdx.x;
    const int l = t & 63, w = t >> 6;
    const int b = blockIdx.y;
    const int i0 = blockIdx.x * 16;
    for (int k = t; k < 1024; k += 256) {
        const float* c = coords + ((size_t)b*1024 + k)*3;
        float cx = c[0], cy = c[1], cz = c[2];
        sc[k] = make_float4(cx, cy, cz, cx*cx + cy*cy + cz*cz);
    }
    __syncthreads();
    const float p = psq[0];
    const int r = t >> 4, jg = t & 15;
    const float4 ci = sc[i0 + r];
    u32x4 pk0, pk1, pk2, pk3, pk4, pk5, pk6, pk7;
    u32x4* pk[8] = {&pk0,&pk1,&pk2,&pk3,&pk4,&pk5,&pk6,&pk7};
    float rsum = 0.f;
#pragma unroll
    for (int pp = 0; pp < 8; ++pp) {
        const int jb = pp*128 + jg*8;
        u32x4 v;
#pragma unroll
        for (int e = 0; e < 4; ++e) {
            float4 cj0 = sc[jb + 2*e], cj1 = sc[jb + 2*e + 1];
            float d0 = ci.w + cj0.w - 2.f*(ci.x*cj0.x + ci.y*cj0.y + ci.z*cj0.z);
            float d1 = ci.w + cj1.w - 2.f*(ci.x*cj1.x + ci.y*cj1.y + ci.z*cj1.z);
            unsigned short h0 = f2bf(__expf(__expf(-d0 * p)));
            unsigned short h1 = f2bf(__expf(__expf(-d1 * p)));
            rsum += bf2f(h0) + bf2f(h1);
            v[e] = (unsigned)h0 | ((unsigned)h1 << 16);
        }
        *pk[pp] = v;
    }
    rsum += __shfl_xor(rsum, 1);
    rsum += __shfl_xor(rsum, 2);
    rsum += __shfl_xor(rsum, 4);
    rsum += __shfl_xor(rsum, 8);
    const float rinv = 1.f / rsum;
    unsigned short* dst = Tg + ((size_t)(b*1024 + i0 + r))*1024;
#pragma unroll
    for (int pp = 0; pp < 8; ++pp) {
        u32x4 u = *pk[pp], v;
        float c[8];
#pragma unroll
        for (int e = 0; e < 4; ++e) {
            unsigned uu = u[e];
            unsigned short nl = f2bf(bf2f((unsigned short)(uu & 0xffffu)) * rinv);
            unsigned short nh = f2bf(bf2f((unsigned short)(uu >> 16)) * rinv);
            v[e] = (unsigned)nl | ((unsigned)nh << 16);
            c[2*e]   = bf2f(nl);
            c[2*e+1] = bf2f(nh);
        }
        *(u32x4*)(dst + pp*128 + jg*8) = v;
#pragma unroll
        for (int e = 0; e < 8; ++e) {
            c[e] += __shfl_xor(c[e], 16);
            c[e] += __shfl_xor(c[e], 32);
        }
        if (l < 16) {
            f32x4 a = {c[0], c[1], c[2], c[3]};
            f32x4 d = {c[4], c[5], c[6], c[7]};
            *(f32x4*)&scol[w][pp*128 + jg*8]     = a;
            *(f32x4*)&scol[w][pp*128 + jg*8 + 4] = d;
        }
    }
    __syncthreads();
    const int j0 = t * 4;
    f32x4 s = *(const f32x4*)&scol[0][j0];
    s += *(const f32x4*)&scol[1][j0];
    s += *(const f32x4*)&scol[2][j0];
    s += *(const f32x4*)&scol[3][j0];
    *(f32x4*)(pcol + ((size_t)(b*64 + blockIdx.x))*1024 + j0) = s;
}

// ---------------------------------------------------------------------------
// proj<F>: v/u = x @ Wtop / x @ Wbot (+bias on u). Emits vuT plane
// [b][128 h][1024 i] bf16 (rows 0..63 = v, 64..127 = u).
template<int F>
__global__ __launch_bounds__(256, 2)
void proj(const float* __restrict__ x32, const unsigned short* __restrict__ xR,
          const unsigned short* __restrict__ wpk, const float* __restrict__ bias,
          unsigned short* __restrict__ vuT)
{
    constexpr int KKN = F / 16;
    constexpr int RB  = 2 * F;                    // x-tile row bytes
    constexpr int XS  = 0;
    constexpr int WS  = 64 * RB;
    constexpr int TBO = (F == 128) ? WS : (WS + KKN * 4096);
    constexpr int SMEM = (F == 128) ? (16384 + 32768) : (2048 + 4096 + 16384);
    __shared__ char smem[SMEM];

    const int t = threadIdx.x;
    const int l = t & 63, w = t >> 6;
    const int b = blockIdx.y;
    const int i0g = blockIdx.x * 64;
    const int m31 = l & 31, kg = l >> 5;
    const int mi = w & 1, ntb = (w >> 1) * 2;
    const float bv = bias[0];

    // stage x tile
    if constexpr (F == 128) {
        const int i = t >> 2, q = t & 3;
        const unsigned short* g = xR + ((size_t)(b*1024 + i0g + i))*128 + q*32;
        char* row = smem + XS + i*256;
        const unsigned sw = swz3(i) << 4;
#pragma unroll
        for (int gg = 0; gg < 4; ++gg) {
            u32x4 v = *(const u32x4*)(g + gg*8);
            *(u32x4*)(row + ((q*64 + gg*16) ^ sw)) = v;
        }
    } else {
        const int i = t >> 2, q = t & 3;
        const float* s = x32 + ((size_t)(b*1024 + i0g + i))*16 + q*4;
        unsigned short h0 = f2bf(s[0]), h1 = f2bf(s[1]), h2 = f2bf(s[2]), h3 = f2bf(s[3]);
        u32x2 v = {(unsigned)h0 | ((unsigned)h1 << 16), (unsigned)h2 | ((unsigned)h3 << 16)};
        *(u32x2*)(smem + XS + i*32 + ((q*8) ^ ((i & 1) << 4))) = v;
    }
    // stage packed W (linear)
    {
        u32x4* dstw = (u32x4*)(smem + WS);
        const u32x4* srcw = (const u32x4*)wpk;
        for (int v = t; v < KKN * 256; v += 256) dstw[v] = srcw[v];
    }
    __syncthreads();

    f32x16 acc0, acc1;
#pragma unroll
    for (int r = 0; r < 16; ++r) { acc0[r] = 0.f; acc1[r] = 0.f; }

    const int arow = mi*32 + m31;
    const char* ap = smem + XS + arow * RB;
    const unsigned swA = (F == 128) ? (swz3(arow) << 4) : ((unsigned)(arow & 1) << 4);
#pragma unroll
    for (int kk = 0; kk < KKN; ++kk) {
        bf16x8 a  = ldfrag(ap + ((kk*32 + kg*16) ^ swA));
        bf16x8 b0 = ldfrag(smem + WS + (kk*4 + ntb    )*1024 + l*16);
        bf16x8 b1 = ldfrag(smem + WS + (kk*4 + ntb + 1)*1024 + l*16);
        acc0 = __builtin_amdgcn_mfma_f32_32x32x16_bf16(a, b0, acc0, 0, 0, 0);
        acc1 = __builtin_amdgcn_mfma_f32_32x32x16_bf16(a, b1, acc1, 0, 0, 0);
    }
    __syncthreads();

    // transpose to TB [128 h][64 i] bf16 (swizzled), then coalesced plane write
#pragma unroll
    for (int ntp = 0; ntp < 2; ++ntp) {
        const int nt = ntb + ntp;
        const int prow = nt*32 + m31;
        char* tb = smem + TBO + prow*128;
        const unsigned sw = (unsigned)(prow & 7) << 4;
        const float badd = (nt >= 2) ? bv : 0.f;
#pragma unroll
        for (int r = 0; r < 16; ++r) {
            const int i = mi*32 + (r & 3) + 8*(r >> 2) + 4*kg;
            float z = ((ntp == 0) ? acc0[r] : acc1[r]) + badd;
            *(unsigned short*)(tb + ((i*2) ^ sw)) = f2bf(z);
        }
    }
    __syncthreads();
    {
        const int hh = t >> 1, q = t & 1;
        const char* tb = smem + TBO + hh*128;
        const unsigned sw = (unsigned)(hh & 7) << 4;
        unsigned short* g = vuT + ((size_t)(b*128 + hh))*1024 + i0g + q*32;
#pragma unroll
        for (int gg = 0; gg < 4; ++gg) {
            u32x4 v = *(const u32x4*)(tb + ((q*64 + gg*16) ^ sw));
            *(u32x4*)(g + gg*8) = v;
        }
    }
}

// ---------------------------------------------------------------------------
// spmm: z = P @ v + u; BN affine; emit xnext rows [b][1024 i][128 f] bf16
// (f = 0..63 z', 64..127 relu(z')).
__global__ __launch_bounds__(256, 4)
void spmm(const unsigned short* __restrict__ vuT, const unsigned short* __restrict__ P,
          const float* __restrict__ gamma, const float* __restrict__ beta,
          unsigned short* __restrict__ oxR)
{
    __shared__ char smem[32768];   // PT dbuf [2][8K] @0; VT dbuf [2][8K] @16K
    const int t = threadIdx.x;
    const int l = t & 63, w = t >> 6;
    const int b = blockIdx.y;
    const int i0g = blockIdx.x * 64;
    const int m31 = l & 31, kg = l >> 5;
    const int wh = w >> 1, wi2 = w & 1;

    const int r4 = t >> 2, c4 = t & 3;
    const unsigned short* gp = P   + ((size_t)(b*1024 + i0g + r4))*1024 + c4*16;
    const unsigned short* gv = vuT + ((size_t)(b*128 + r4))*1024 + c4*16;
    u32x4 rp0 = *(const u32x4*)(gp), rp1 = *(const u32x4*)(gp + 8);
    u32x4 rv0 = *(const u32x4*)(gv), rv1 = *(const u32x4*)(gv + 8);
    const unsigned swr = swz3(r4) << 4;
    const int aRow = wh*32 + m31, bRow = wi2*32 + m31;
    const unsigned swA = swz3(aRow) << 4, swB = swz3(bRow) << 4;

    f32x16 acc;
#pragma unroll
    for (int r = 0; r < 16; ++r) acc[r] = 0.f;

    for (int jt = 0; jt < 16; ++jt) {
        const int p = jt & 1;
        {
            char* pt = smem + p*8192 + r4*128;
            *(u32x4*)(pt + ((c4*32     ) ^ swr)) = rp0;
            *(u32x4*)(pt + ((c4*32 + 16) ^ swr)) = rp1;
            char* vt = smem + 16384 + p*8192 + r4*128;
            *(u32x4*)(vt + ((c4*32     ) ^ swr)) = rv0;
            *(u32x4*)(vt + ((c4*32 + 16) ^ swr)) = rv1;
        }
        if (jt < 15) {
            rp0 = *(const u32x4*)(gp + (jt+1)*64);
            rp1 = *(const u32x4*)(gp + (jt+1)*64 + 8);
            rv0 = *(const u32x4*)(gv + (jt+1)*64);
            rv1 = *(const u32x4*)(gv + (jt+1)*64 + 8);
        }
        __syncthreads();
        const char* a_ = smem + 16384 + p*8192 + aRow*128;
        const char* b_ = smem + p*8192 + bRow*128;
#pragma unroll
        for (int kk = 0; kk < 4; ++kk) {
            const unsigned off = kk*32 + kg*16;
            bf16x8 af = ldfrag(a_ + (off ^ swA));
            bf16x8 bf = ldfrag(b_ + (off ^ swB));
            acc = __builtin_amdgcn_mfma_f32_32x32x16_bf16(af, bf, acc, 0, 0, 0);
        }
        __syncthreads();
    }

    // stage u tile [64 h][64 i] linear @0
    {
        const unsigned short* gu = vuT + ((size_t)(b*128 + 64 + r4))*1024 + i0g + c4*16;
        u32x4 u0 = *(const u32x4*)(gu), u1 = *(const u32x4*)(gu + 8);
        *(u32x4*)(smem + r4*128 + c4*32)      = u0;
        *(u32x4*)(smem + r4*128 + c4*32 + 16) = u1;
    }
    __syncthreads();

    const float bns = rsqrtf(1.f + 1e-3f);
    const int ii = wi2*32 + m31;
    char* ZT = smem + 8192;      // [64 i][256 B] bf16, swizzled
    const unsigned swz_i = (unsigned)(ii & 7) << 4;
#pragma unroll
    for (int r = 0; r < 16; ++r) {
        const int h = wh*32 + (r & 3) + 8*(r >> 2) + 4*kg;
        float u = bf2f(*(const unsigned short*)(smem + h*128 + ii*2));
        float z = (acc[r] + u) * (gamma[h] * bns) + beta[h];
        *(unsigned short*)(ZT + ii*256 + (((unsigned)(h*2)) ^ swz_i))        = f2bf(z);
        *(unsigned short*)(ZT + ii*256 + (((unsigned)((64 + h)*2)) ^ swz_i)) = f2bf(fmaxf(z, 0.f));
    }
    __syncthreads();
    {
        const int i = t >> 2, q = t & 3;
        const char* zr = ZT + i*256;
        const unsigned sw = (unsigned)(i & 7) << 4;
        unsigned short* g = oxR + ((size_t)(b*1024 + i0g + i))*128 + q*32;
#pragma unroll
        for (int gg = 0; gg < 4; ++gg) {
            u32x4 v = *(const u32x4*)(zr + ((q*64 + gg*16) ^ sw));
            *(u32x4*)(g + gg*8) = v;
        }
    }
}

// ---------------------------------------------------------------------------
// finalize: logits[h] = ( sum_j colsum[j]*v3[j][h] + sum_i u3[i][h] ) / 1024;
// out = softmax(logits).  (b3 already folded into u3 by proj3.)
__global__ __launch_bounds__(256)
void finalize(const float* __restrict__ pcol, const unsigned short* __restrict__ vuT3,
              float* __restrict__ out)
{
    __shared__ float red[2056];
    const int b = blockIdx.x, t = threadIdx.x;
    const int j0 = t * 4;
    f32x4 cs = {0.f, 0.f, 0.f, 0.f};
    for (int p = 0; p < 64; ++p)
        cs += *(const f32x4*)(pcol + ((size_t)(b*64 + p))*1024 + j0);
    float lv[4], lu[4];
#pragma unroll
    for (int h = 0; h < 4; ++h) {
        const unsigned short* vr = vuT3 + ((size_t)(b*128 + h))*1024 + j0;
        lv[h] = cs[0]*bf2f(vr[0]) + cs[1]*bf2f(vr[1]) + cs[2]*bf2f(vr[2]) + cs[3]*bf2f(vr[3]);
        const unsigned short* ur = vuT3 + ((size_t)(b*128 + 64 + h))*1024 + j0;
        lu[h] = bf2f(ur[0]) + bf2f(ur[1]) + bf2f(ur[2]) + bf2f(ur[3]);
    }
#pragma unroll
    for (int q = 0; q < 4; ++q) { red[t*8 + q] = lv[q]; red[t*8 + 4 + q] = lu[q]; }
    __syncthreads();
    if (t < 8) {
        float s = 0.f;
        for (int k = 0; k < 256; ++k) s += red[k*8 + t];
        red[2048 + t] = s;
    }
    __syncthreads();
    if (t == 0) {
        float v[4];
#pragma unroll
        for (int h = 0; h < 4; ++h) v[h] = (red[2048 + h] + red[2048 + 4 + h]) * (1.f / 1024.f);
        const float m = fmaxf(fmaxf(v[0], v[1]), fmaxf(v[2], v[3]));
        float e[4], se = 0.f;
#pragma unroll
        for (int h = 0; h < 4; ++h) { e[h] = __expf(v[h] - m); se += e[h]; }
        const float inv = 1.f / se;
#pragma unroll
        for (int h = 0; h < 4; ++h) out[b*4 + h] = e[h] * inv;
    }
}

extern "C" void kernel_launch(void* const* d_in, const int* in_sizes, int n_in,
                              void* d_out, int out_size, void* d_ws, size_t ws_size,
                              hipStream_t stream)
{
    const float* x   = (const float*)d_in[0];
    const float* co  = (const float*)d_in[1];
    const float* psq = (const float*)d_in[2];
    const float* W0  = (const float*)d_in[3];
    const float* W1  = (const float*)d_in[4];
    const float* W2  = (const float*)d_in[5];
    const float* W3  = (const float*)d_in[6];
    const float* b0  = (const float*)d_in[7];
    const float* b1  = (const float*)d_in[8];
    const float* b2  = (const float*)d_in[9];
    const float* b3  = (const float*)d_in[10];
    const float* g0  = (const float*)d_in[11];
    const float* be0 = (const float*)d_in[12];
    const float* g1  = (const float*)d_in[13];
    const float* be1 = (const float*)d_in[14];
    const float* g2  = (const float*)d_in[15];
    const float* be2 = (const float*)d_in[16];

    char* ws = (char*)d_ws;
    const size_t MB = (size_t)1 << 20;
    unsigned short* P   = (unsigned short*)(ws);              // 64 MB
    float*          pcol= (float*)(ws + 64*MB);               // 8 MB
    unsigned short* vuA = (unsigned short*)(ws + 72*MB);      // 8 MB
    unsigned short* vuB = (unsigned short*)(ws + 80*MB);      // 8 MB
    unsigned short* xRa = (unsigned short*)(ws + 88*MB);      // 8 MB
    unsigned short* xRb = (unsigned short*)(ws + 96*MB);      // 8 MB
    unsigned short* wpk = (unsigned short*)(ws + 104*MB);     // 100 KB

    prep<<<dim3(200), 256, 0, stream>>>(W0, W1, W2, W3, wpk);
    tgen<<<dim3(64, 32), 256, 0, stream>>>(co, psq, P, pcol);

    dim3 grid(16, 32);
    proj<16> <<<grid, 256, 0, stream>>>(x, nullptr, wpk,         b0, vuA);
    spmm     <<<grid, 256, 0, stream>>>(vuA, P, g0, be0, xRa);
    proj<128><<<grid, 256, 0, stream>>>(nullptr, xRa, wpk + 2048,  b1, vuB);
    spmm     <<<grid, 256, 0, stream>>>(vuB, P, g1, be1, xRb);
    proj<128><<<grid, 256, 0, stream>>>(nullptr, xRb, wpk + 18432, b2, vuA);
    spmm     <<<grid, 256, 0, stream>>>(vuA, P, g2, be2, xRa);
    proj<128><<<grid, 256, 0, stream>>>(nullptr, xRa, wpk + 34816, b3, vuB);
    finalize <<<dim3(32), 256, 0, stream>>>(pcol, vuB, (float*)d_out);
}

// Round 7
// 193.567 us; speedup vs baseline: 1.2995x; 1.2995x over previous
//
#include <hip/hip_runtime.h>
#include <math.h>

typedef __attribute__((ext_vector_type(8)))  __bf16   bf16x8;
typedef __attribute__((ext_vector_type(4)))  float    f32x4;
typedef __attribute__((ext_vector_type(16))) float    f32x16;
typedef __attribute__((ext_vector_type(4)))  unsigned u32x4;
typedef __attribute__((ext_vector_type(2)))  unsigned u32x2;

__device__ __forceinline__ unsigned short f2bf(float f) {
    unsigned u = __builtin_bit_cast(unsigned, f);
    u += 0x7fffu + ((u >> 16) & 1u);
    return (unsigned short)(u >> 16);
}
__device__ __forceinline__ float bf2f(unsigned short b) {
    unsigned u = ((unsigned)b) << 16;
    return __builtin_bit_cast(float, u);
}
__device__ __forceinline__ unsigned swz3(int key) { return (unsigned)((key ^ (key >> 3)) & 7); }
__device__ __forceinline__ bf16x8 ldfrag(const char* p) { return __builtin_bit_cast(bf16x8, *(const u32x4*)p); }

// ---------------------------------------------------------------------------
// prep: pack W into MFMA A-fragment layout (bf16).
// frag element (kk, nt, lane, e) = W[f][h]:
//   f = kk*16 + (lane>>5)*8 + e + (nt>=2 ? F : 0)   (nt>=2 -> Wbot)
//   h = (nt&1)*32 + (lane&31)
// Flat: wpk[base + ((kk*4+nt)*64 + lane)*8 + e].
// Bases (elems): L0 @0 (2048), L1 @2048, L2 @18432, L3 @34816 (16384 each).
__global__ __launch_bounds__(256)
void prep(const float* __restrict__ W0, const float* __restrict__ W1,
          const float* __restrict__ W2, const float* __restrict__ W3,
          unsigned short* __restrict__ wpk)
{
    int id = blockIdx.x * 256 + threadIdx.x;
    if (id >= 51200) return;
    float v;
    if (id < 2048) {
        int j = id;
        int e = j & 7, lane = (j >> 3) & 63, nt = (j >> 9) & 3;
        int f = ((lane >> 5) << 3) + e + ((nt >= 2) ? 16 : 0);
        int h = ((nt & 1) << 5) + (lane & 31);
        v = W0[f * 64 + h];
    } else {
        int jid = id - 2048;
        int l = jid >> 14;            // 0,1,2 -> layers 1,2,3
        int j = jid & 16383;
        int e = j & 7, lane = (j >> 3) & 63, nt = (j >> 9) & 3, kk = j >> 11;
        int f = kk * 16 + ((lane >> 5) << 3) + e + ((nt >= 2) ? 128 : 0);
        int h = ((nt & 1) << 5) + (lane & 31);
        const float* W = (l == 0) ? W1 : (l == 1) ? W2 : W3;
        int H = (l == 2) ? 4 : 64;
        v = (h < H) ? W[f * H + h] : 0.f;
    }
    wpk[id] = f2bf(v);
}

// ---------------------------------------------------------------------------
// tgen: P[b][i][j] = round_bf16( round_bf16(exp(exp(-d*p))) / rowsum ).
// sc is SKEWED (idx = k + (k>>3)) so the jg*8-strided reads are conflict-free.
// Normalized tile staged in LDS -> colsum partials + one flat coalesced store.
__global__ __launch_bounds__(256, 3)
void tgen(const float* __restrict__ coords, const float* __restrict__ psq,
          unsigned short* __restrict__ Tg, float* __restrict__ pcol)
{
    __shared__ float4 sc[1152];          // skewed coords+norm
    __shared__ char   tile[16 * 2048];   // [16 r][1024 j] bf16
    const int t = threadIdx.x;
    const int b = blockIdx.y;
    const int i0 = blockIdx.x * 16;
    for (int k = t; k < 1024; k += 256) {
        const float* c = coords + ((size_t)b*1024 + k)*3;
        float cx = c[0], cy = c[1], cz = c[2];
        sc[k + (k >> 3)] = make_float4(cx, cy, cz, cx*cx + cy*cy + cz*cz);
    }
    __syncthreads();
    const float p = psq[0];
    const int r = t >> 4, jg = t & 15;
    const int kci = i0 + r;
    const float4 ci = sc[kci + (kci >> 3)];
    u32x4 raw[8];
    float rsum = 0.f;
#pragma unroll
    for (int pp = 0; pp < 8; ++pp) {
        const int base = pp*144 + jg*9;   // skewed index of j = pp*128 + jg*8
        u32x4 v;
#pragma unroll
        for (int e = 0; e < 4; ++e) {
            float4 cj0 = sc[base + 2*e], cj1 = sc[base + 2*e + 1];
            float d0 = ci.w + cj0.w - 2.f*(ci.x*cj0.x + ci.y*cj0.y + ci.z*cj0.z);
            float d1 = ci.w + cj1.w - 2.f*(ci.x*cj1.x + ci.y*cj1.y + ci.z*cj1.z);
            unsigned short h0 = f2bf(__expf(__expf(-d0 * p)));
            unsigned short h1 = f2bf(__expf(__expf(-d1 * p)));
            rsum += bf2f(h0) + bf2f(h1);
            v[e] = (unsigned)h0 | ((unsigned)h1 << 16);
        }
        raw[pp] = v;
    }
    rsum += __shfl_xor(rsum, 1);
    rsum += __shfl_xor(rsum, 2);
    rsum += __shfl_xor(rsum, 4);
    rsum += __shfl_xor(rsum, 8);
    const float rinv = 1.f / rsum;
    char* trow = tile + r * 2048;
#pragma unroll
    for (int pp = 0; pp < 8; ++pp) {
        u32x4 u = raw[pp], v;
#pragma unroll
        for (int e = 0; e < 4; ++e) {
            unsigned uu = u[e];
            unsigned short nl = f2bf(bf2f((unsigned short)(uu & 0xffffu)) * rinv);
            unsigned short nh = f2bf(bf2f((unsigned short)(uu >> 16)) * rinv);
            v[e] = (unsigned)nl | ((unsigned)nh << 16);
        }
        *(u32x4*)(trow + (pp*128 + jg*8)*2) = v;
    }
    __syncthreads();
    {   // column-sum partial over the 16 rows
        const int j0 = t * 4;
        f32x4 cs = {0.f, 0.f, 0.f, 0.f};
#pragma unroll
        for (int rr = 0; rr < 16; ++rr) {
            u32x2 u = *(const u32x2*)(tile + rr*2048 + j0*2);
            cs[0] += bf2f((unsigned short)(u[0] & 0xffffu));
            cs[1] += bf2f((unsigned short)(u[0] >> 16));
            cs[2] += bf2f((unsigned short)(u[1] & 0xffffu));
            cs[3] += bf2f((unsigned short)(u[1] >> 16));
        }
        *(f32x4*)(pcol + ((size_t)(b*64 + blockIdx.x))*1024 + j0) = cs;
    }
    {   // flat coalesced store: rows i0..i0+15 are contiguous in Tg
        const u32x4* src = (const u32x4*)tile;
        u32x4* dst = (u32x4*)(Tg + ((size_t)(b*1024 + i0))*1024);
        for (int v = t; v < 2048; v += 256) dst[v] = src[v];
    }
}

// ---------------------------------------------------------------------------
// proj0: v/u = bf16(x) @ W0top / W0bot (+b0 on u). Emits vuT [b][128 h][1024 i].
__global__ __launch_bounds__(256, 2)
void proj0(const float* __restrict__ x32, const unsigned short* __restrict__ wpk,
           const float* __restrict__ bias, unsigned short* __restrict__ vuT)
{
    __shared__ char smem[2048 + 4096 + 16384];
    constexpr int XS = 0, WS = 2048, TBO = 6144;
    const int t = threadIdx.x;
    const int l = t & 63, w = t >> 6;
    const int b = blockIdx.y;
    const int i0g = blockIdx.x * 64;
    const int m31 = l & 31, kg = l >> 5;
    const int mi = w & 1, ntb = (w >> 1) * 2;
    const float bv = bias[0];

    {   // stage x tile [64 i][16 f] bf16
        const int i = t >> 2, q = t & 3;
        const float* s = x32 + ((size_t)(b*1024 + i0g + i))*16 + q*4;
        unsigned short h0 = f2bf(s[0]), h1 = f2bf(s[1]), h2 = f2bf(s[2]), h3 = f2bf(s[3]);
        u32x2 v = {(unsigned)h0 | ((unsigned)h1 << 16), (unsigned)h2 | ((unsigned)h3 << 16)};
        *(u32x2*)(smem + XS + i*32 + ((q*8) ^ ((i & 1) << 4))) = v;
    }
    {   // stage packed W0 (linear)
        u32x4* dstw = (u32x4*)(smem + WS);
        const u32x4* srcw = (const u32x4*)wpk;
        if (t < 256) dstw[t] = srcw[t];
    }
    __syncthreads();

    f32x16 acc0, acc1;
#pragma unroll
    for (int r = 0; r < 16; ++r) { acc0[r] = 0.f; acc1[r] = 0.f; }
    const int arow = mi*32 + m31;
    const char* ap = smem + XS + arow * 32;
    const unsigned swA = (unsigned)(arow & 1) << 4;
    {
        bf16x8 a  = ldfrag(ap + ((kg*16) ^ swA));
        bf16x8 b0 = ldfrag(smem + WS + (ntb    )*1024 + l*16);
        bf16x8 b1 = ldfrag(smem + WS + (ntb + 1)*1024 + l*16);
        acc0 = __builtin_amdgcn_mfma_f32_32x32x16_bf16(a, b0, acc0, 0, 0, 0);
        acc1 = __builtin_amdgcn_mfma_f32_32x32x16_bf16(a, b1, acc1, 0, 0, 0);
    }
    __syncthreads();
#pragma unroll
    for (int ntp = 0; ntp < 2; ++ntp) {
        const int nt = ntb + ntp;
        const int prow = nt*32 + m31;
        char* tb = smem + TBO + prow*128;
        const unsigned sw = (unsigned)(prow & 7) << 4;
        const float badd = (nt >= 2) ? bv : 0.f;
#pragma unroll
        for (int r = 0; r < 16; ++r) {
            const int i = mi*32 + (r & 3) + 8*(r >> 2) + 4*kg;
            float z = ((ntp == 0) ? acc0[r] : acc1[r]) + badd;
            *(unsigned short*)(tb + ((i*2) ^ sw)) = f2bf(z);
        }
    }
    __syncthreads();
    {
        const int hh = t >> 1, q = t & 1;
        const char* tb = smem + TBO + hh*128;
        const unsigned sw = (unsigned)(hh & 7) << 4;
        unsigned short* g = vuT + ((size_t)(b*128 + hh))*1024 + i0g + q*32;
#pragma unroll
        for (int gg = 0; gg < 4; ++gg) {
            u32x4 v = *(const u32x4*)(tb + ((q*64 + gg*16) ^ sw));
            *(u32x4*)(g + gg*8) = v;
        }
    }
}

// ---------------------------------------------------------------------------
// fspmm: z = P @ v + u; BN; x' = concat(z', relu z'); then FUSED next-layer
// projection v',u' = x' @ W'top / W'bot (+b' on u'). Emits ovuT planes.
__global__ __launch_bounds__(256, 2)
void fspmm(const unsigned short* __restrict__ vuT, const unsigned short* __restrict__ P,
           const float* __restrict__ gamma, const float* __restrict__ beta,
           const unsigned short* __restrict__ wpkN, const float* __restrict__ biasN,
           unsigned short* __restrict__ ovuT)
{
    __shared__ char smem[32768];   // PT dbuf [2][8K] @0; VT dbuf [2][8K] @16K
    const int t = threadIdx.x;
    const int l = t & 63, w = t >> 6;
    const int b = blockIdx.y;
    const int i0g = blockIdx.x * 64;
    const int m31 = l & 31, kg = l >> 5;
    const int wh = w >> 1, wi2 = w & 1;
    const float bvN = biasN[0];

    const int r4 = t >> 2, c4 = t & 3;
    const unsigned short* gp = P   + ((size_t)(b*1024 + i0g + r4))*1024 + c4*16;
    const unsigned short* gv = vuT + ((size_t)(b*128 + r4))*1024 + c4*16;
    u32x4 rp0 = *(const u32x4*)(gp), rp1 = *(const u32x4*)(gp + 8);
    u32x4 rv0 = *(const u32x4*)(gv), rv1 = *(const u32x4*)(gv + 8);
    const unsigned swr = swz3(r4) << 4;
    const int aRow = wh*32 + m31, bRow = wi2*32 + m31;
    const unsigned swA = swz3(aRow) << 4, swB = swz3(bRow) << 4;

    f32x16 acc;
#pragma unroll
    for (int r = 0; r < 16; ++r) acc[r] = 0.f;

    for (int jt = 0; jt < 16; ++jt) {
        const int p = jt & 1;
        {
            char* pt = smem + p*8192 + r4*128;
            *(u32x4*)(pt + ((c4*32     ) ^ swr)) = rp0;
            *(u32x4*)(pt + ((c4*32 + 16) ^ swr)) = rp1;
            char* vt = smem + 16384 + p*8192 + r4*128;
            *(u32x4*)(vt + ((c4*32     ) ^ swr)) = rv0;
            *(u32x4*)(vt + ((c4*32 + 16) ^ swr)) = rv1;
        }
        if (jt < 15) {
            rp0 = *(const u32x4*)(gp + (jt+1)*64);
            rp1 = *(const u32x4*)(gp + (jt+1)*64 + 8);
            rv0 = *(const u32x4*)(gv + (jt+1)*64);
            rv1 = *(const u32x4*)(gv + (jt+1)*64 + 8);
        }
        __syncthreads();
        const char* a_ = smem + 16384 + p*8192 + aRow*128;
        const char* b_ = smem + p*8192 + bRow*128;
#pragma unroll
        for (int kk = 0; kk < 4; ++kk) {
            const unsigned off = kk*32 + kg*16;
            bf16x8 af = ldfrag(a_ + (off ^ swA));
            bf16x8 bf = ldfrag(b_ + (off ^ swB));
            acc = __builtin_amdgcn_mfma_f32_32x32x16_bf16(af, bf, acc, 0, 0, 0);
        }
        __syncthreads();
    }

    // ---- epilogue: z, BN, x' tile ----
    {   // stage u tile [64 h][64 i] linear @0
        const unsigned short* gu = vuT + ((size_t)(b*128 + 64 + r4))*1024 + i0g + c4*16;
        u32x4 u0 = *(const u32x4*)(gu), u1 = *(const u32x4*)(gu + 8);
        *(u32x4*)(smem + r4*128 + c4*32)      = u0;
        *(u32x4*)(smem + r4*128 + c4*32 + 16) = u1;
    }
    __syncthreads();
    const float bns = rsqrtf(1.f + 1e-3f);
    const int ii = wi2*32 + m31;
    char* ZT = smem + 16384;     // [64 i][256 B] bf16, swizzled by (i&7)
    const unsigned swzi = (unsigned)(ii & 7) << 4;
#pragma unroll
    for (int r = 0; r < 16; ++r) {
        const int h = wh*32 + (r & 3) + 8*(r >> 2) + 4*kg;
        float u = bf2f(*(const unsigned short*)(smem + h*128 + ii*2));
        float z = (acc[r] + u) * (gamma[h] * bns) + beta[h];
        *(unsigned short*)(ZT + ii*256 + (((unsigned)(h*2)) ^ swzi))        = f2bf(z);
        *(unsigned short*)(ZT + ii*256 + (((unsigned)((64 + h)*2)) ^ swzi)) = f2bf(fmaxf(z, 0.f));
    }
    __syncthreads();

    // ---- fused next-layer projection: A = W' frags (global), B = x' (ZT) ----
    f32x16 vac, uac;
#pragma unroll
    for (int r = 0; r < 16; ++r) { vac[r] = 0.f; uac[r] = bvN; }
    const char* bx_base = ZT + ii*256;
#pragma unroll
    for (int kk = 0; kk < 8; ++kk) {
        bf16x8 awv = __builtin_bit_cast(bf16x8, *(const u32x4*)(wpkN + ((size_t)((kk*4 + wh    )*64 + l))*8));
        bf16x8 awu = __builtin_bit_cast(bf16x8, *(const u32x4*)(wpkN + ((size_t)((kk*4 + wh + 2)*64 + l))*8));
        bf16x8 bx  = ldfrag(bx_base + ((kk*32 + kg*16) ^ swzi));
        vac = __builtin_amdgcn_mfma_f32_32x32x16_bf16(awv, bx, vac, 0, 0, 0);
        uac = __builtin_amdgcn_mfma_f32_32x32x16_bf16(awu, bx, uac, 0, 0, 0);
    }
    __syncthreads();
    {   // transpose to TB [128 h'][128 B] @0, then coalesced plane write
        char* TB = smem;
#pragma unroll
        for (int r = 0; r < 16; ++r) {
            const int hv = wh*32 + (r & 3) + 8*(r >> 2) + 4*kg;
            const unsigned sw = (unsigned)(hv & 7) << 4;
            *(unsigned short*)(TB + hv*128        + ((ii*2) ^ sw)) = f2bf(vac[r]);
            *(unsigned short*)(TB + (hv + 64)*128 + ((ii*2) ^ sw)) = f2bf(uac[r]);
        }
    }
    __syncthreads();
    {
        const int hh = t >> 1, q = t & 1;
        const char* tb = smem + hh*128;
        const unsigned sw = (unsigned)(hh & 7) << 4;
        unsigned short* g = ovuT + ((size_t)(b*128 + hh))*1024 + i0g + q*32;
#pragma unroll
        for (int gg = 0; gg < 4; ++gg) {
            u32x4 v = *(const u32x4*)(tb + ((q*64 + gg*16) ^ sw));
            *(u32x4*)(g + gg*8) = v;
        }
    }
}

// ---------------------------------------------------------------------------
// finalize: logits[h] = ( colsum(P)·v3 + sum_i u3 ) / 1024; out = softmax.
__global__ __launch_bounds__(256)
void finalize(const float* __restrict__ pcol, const unsigned short* __restrict__ vuT3,
              float* __restrict__ out)
{
    __shared__ float red[2056];
    const int b = blockIdx.x, t = threadIdx.x;
    const int j0 = t * 4;
    f32x4 cs = {0.f, 0.f, 0.f, 0.f};
    for (int p = 0; p < 64; ++p)
        cs += *(const f32x4*)(pcol + ((size_t)(b*64 + p))*1024 + j0);
    float lv[4], lu[4];
#pragma unroll
    for (int h = 0; h < 4; ++h) {
        const unsigned short* vr = vuT3 + ((size_t)(b*128 + h))*1024 + j0;
        lv[h] = cs[0]*bf2f(vr[0]) + cs[1]*bf2f(vr[1]) + cs[2]*bf2f(vr[2]) + cs[3]*bf2f(vr[3]);
        const unsigned short* ur = vuT3 + ((size_t)(b*128 + 64 + h))*1024 + j0;
        lu[h] = bf2f(ur[0]) + bf2f(ur[1]) + bf2f(ur[2]) + bf2f(ur[3]);
    }
#pragma unroll
    for (int q = 0; q < 4; ++q) { red[t*8 + q] = lv[q]; red[t*8 + 4 + q] = lu[q]; }
    __syncthreads();
    if (t < 8) {
        float s = 0.f;
        for (int k = 0; k < 256; ++k) s += red[k*8 + t];
        red[2048 + t] = s;
    }
    __syncthreads();
    if (t == 0) {
        float v[4];
#pragma unroll
        for (int h = 0; h < 4; ++h) v[h] = (red[2048 + h] + red[2048 + 4 + h]) * (1.f / 1024.f);
        const float m = fmaxf(fmaxf(v[0], v[1]), fmaxf(v[2], v[3]));
        float e[4], se = 0.f;
#pragma unroll
        for (int h = 0; h < 4; ++h) { e[h] = __expf(v[h] - m); se += e[h]; }
        const float inv = 1.f / se;
#pragma unroll
        for (int h = 0; h < 4; ++h) out[b*4 + h] = e[h] * inv;
    }
}

extern "C" void kernel_launch(void* const* d_in, const int* in_sizes, int n_in,
                              void* d_out, int out_size, void* d_ws, size_t ws_size,
                              hipStream_t stream)
{
    const float* x   = (const float*)d_in[0];
    const float* co  = (const float*)d_in[1];
    const float* psq = (const float*)d_in[2];
    const float* W0  = (const float*)d_in[3];
    const float* W1  = (const float*)d_in[4];
    const float* W2  = (const float*)d_in[5];
    const float* W3  = (const float*)d_in[6];
    const float* b0  = (const float*)d_in[7];
    const float* b1  = (const float*)d_in[8];
    const float* b2  = (const float*)d_in[9];
    const float* b3  = (const float*)d_in[10];
    const float* g0  = (const float*)d_in[11];
    const float* be0 = (const float*)d_in[12];
    const float* g1  = (const float*)d_in[13];
    const float* be1 = (const float*)d_in[14];
    const float* g2  = (const float*)d_in[15];
    const float* be2 = (const float*)d_in[16];

    char* ws = (char*)d_ws;
    const size_t MB = (size_t)1 << 20;
    unsigned short* P    = (unsigned short*)(ws);             // 64 MB
    float*          pcol = (float*)(ws + 64*MB);              // 8 MB
    unsigned short* vuA  = (unsigned short*)(ws + 72*MB);     // 8 MB
    unsigned short* vuB  = (unsigned short*)(ws + 80*MB);     // 8 MB
    unsigned short* wpk  = (unsigned short*)(ws + 88*MB);     // 100 KB

    prep<<<dim3(200), 256, 0, stream>>>(W0, W1, W2, W3, wpk);
    tgen<<<dim3(64, 32), 256, 0, stream>>>(co, psq, P, pcol);

    dim3 grid(16, 32);
    proj0<<<grid, 256, 0, stream>>>(x, wpk, b0, vuA);
    fspmm<<<grid, 256, 0, stream>>>(vuA, P, g0, be0, wpk + 2048,  b1, vuB);
    fspmm<<<grid, 256, 0, stream>>>(vuB, P, g1, be1, wpk + 18432, b2, vuA);
    fspmm<<<grid, 256, 0, stream>>>(vuA, P, g2, be2, wpk + 34816, b3, vuB);
    finalize<<<dim3(32), 256, 0, stream>>>(pcol, vuB, (float*)d_out);
}